// Round 1
// baseline (518.294 us; speedup 1.0000x reference)
//
#include <hip/hip_runtime.h>
#include <hip/hip_bf16.h>
#include <math.h>

// Problem constants (from reference): B=4, T=512, S=1024, H=768, V=50257
#define BB 4
#define TT 512
#define SS 1024
#define HH 768
#define VV 50257

// ---------------------------------------------------------------------------
// Kernel A: projections.
//   src_proj[b,s] = dot(src[b,s,:], W[0:H])          rows 0..4095
//   tgt_proj[b,t] = dot(tgt[b,t,:], W[H:2H]) + bias  rows 4096..6143
// One wave (64 lanes) per row; each lane reads 3 float4s (768 floats/row).
// ---------------------------------------------------------------------------
__global__ __launch_bounds__(256) void proj_kernel(
    const float* __restrict__ src,   // [B*S, H]
    const float* __restrict__ tgt,   // [B*T, H]
    const float* __restrict__ W,     // [2H]
    const float* __restrict__ bptr,  // [1]
    float* __restrict__ src_proj,    // [B*S]
    float* __restrict__ tgt_proj)    // [B*T]
{
    const int wave = threadIdx.x >> 6;
    const int lane = threadIdx.x & 63;
    const int row  = blockIdx.x * 4 + wave;   // 0 .. 6143

    const float* vec;
    const float* w;
    if (row < BB * SS) {
        vec = src + (size_t)row * HH;
        w   = W;
    } else {
        vec = tgt + (size_t)(row - BB * SS) * HH;
        w   = W + HH;
    }
    const float4* v4 = (const float4*)vec;   // 192 float4 per row
    const float4* w4 = (const float4*)w;

    float acc = 0.f;
#pragma unroll
    for (int k = 0; k < 3; ++k) {
        float4 a = v4[k * 64 + lane];
        float4 b = w4[k * 64 + lane];
        acc += a.x * b.x + a.y * b.y + a.z * b.z + a.w * b.w;
    }
    // wave64 shuffle reduction
#pragma unroll
    for (int off = 32; off > 0; off >>= 1) acc += __shfl_down(acc, off);

    if (lane == 0) {
        if (row < BB * SS) src_proj[row] = acc;
        else               tgt_proj[row - BB * SS] = acc + bptr[0];
    }
}

// ---------------------------------------------------------------------------
// Kernel B: one block per (b,t) row.
//   1) zero the 50257-float logits row (float4 stores, alignment-fixed head)
//   2) scatter: atomicAdd(row[ids[b,s]], attn[b,t,s]) for s in [0,S)
//   3) p_gen[b,t] = sigmoid( sum_s attn*src_proj[b,s] + tgt_proj[b,t] )
// Row stays resident in L2 (201 KB) so the atomics hit L2, not HBM.
// ---------------------------------------------------------------------------
__global__ __launch_bounds__(256) void row_kernel(
    const int*   __restrict__ ids,       // [B, S]
    const float* __restrict__ attn,      // [B*T, S]
    const float* __restrict__ src_proj,  // [B, S]
    const float* __restrict__ tgt_proj,  // [B*T]
    float* __restrict__ out)             // [B*T (p_gen) | B*T*V (logits)]
{
    const int row = blockIdx.x;          // 0 .. B*T-1
    const int b   = row >> 9;            // row / T (T = 512)
    const int tid = threadIdx.x;

    float* logits = out + (BB * TT) + (size_t)row * VV;

    // ---- zero the row (V floats), handling 16B misalignment (V is odd) ----
    uintptr_t addr = (uintptr_t)logits;
    int head = (int)(((16u - (addr & 15u)) & 15u) >> 2);   // 0..3 floats
    if (tid < head) logits[tid] = 0.f;
    const int n4 = (VV - head) >> 2;
    float4* p4 = (float4*)(logits + head);
    const float4 z4 = make_float4(0.f, 0.f, 0.f, 0.f);
    for (int i = tid; i < n4; i += 256) p4[i] = z4;
    const int done = head + (n4 << 2);
    for (int i = done + tid; i < VV; i += 256) logits[i] = 0.f;

    __syncthreads();

    // ---- scatter + p_gen partial dot ----
    const float* attn_row = attn + (size_t)row * SS;
    const int*   ids_b    = ids + b * SS;
    const float* sp_b     = src_proj + b * SS;

    float acc = 0.f;
#pragma unroll
    for (int k = 0; k < SS / 256; ++k) {
        const int s = tid + k * 256;
        const float a = attn_row[s];
        const int   id = ids_b[s];
        atomicAdd(logits + id, a);
        acc += a * sp_b[s];
    }

    // ---- block reduce acc (4 waves) ----
#pragma unroll
    for (int off = 32; off > 0; off >>= 1) acc += __shfl_down(acc, off);
    __shared__ float wsum[4];
    if ((tid & 63) == 0) wsum[tid >> 6] = acc;
    __syncthreads();
    if (tid == 0) {
        const float sum = wsum[0] + wsum[1] + wsum[2] + wsum[3];
        const float x = sum + tgt_proj[row];
        out[row] = 1.f / (1.f + expf(-x));
    }
}

extern "C" void kernel_launch(void* const* d_in, const int* in_sizes, int n_in,
                              void* d_out, int out_size, void* d_ws, size_t ws_size,
                              hipStream_t stream) {
    const int*   ids  = (const int*)d_in[0];    // [B,S]
    const float* attn = (const float*)d_in[1];  // [B,T,S]
    const float* src  = (const float*)d_in[2];  // [B,S,H]
    const float* tgt  = (const float*)d_in[3];  // [B,T,H]
    const float* W    = (const float*)d_in[4];  // [2H,1]
    const float* bp   = (const float*)d_in[5];  // [1]

    float* out = (float*)d_out;                 // [B*T + B*T*V]
    float* ws  = (float*)d_ws;
    float* src_proj = ws;                       // [B*S] = 4096 floats
    float* tgt_proj = ws + BB * SS;             // [B*T] = 2048 floats

    // Kernel A: 6144 rows, 4 waves/block -> 1536 blocks
    proj_kernel<<<(BB * SS + BB * TT) / 4, 256, 0, stream>>>(
        src, tgt, W, bp, src_proj, tgt_proj);

    // Kernel B: one block per (b,t) row
    row_kernel<<<BB * TT, 256, 0, stream>>>(ids, attn, src_proj, tgt_proj, out);
}

// Round 2
// 466.596 us; speedup vs baseline: 1.1108x; 1.1108x over previous
//
#include <hip/hip_runtime.h>
#include <hip/hip_bf16.h>
#include <math.h>

// Problem constants: B=4, T=512, S=1024, H=768, V=50257
#define BB 4
#define TT 512
#define SS 1024
#define HH 768
#define VV 50257
#define NW 1571   // ceil(V/32) bitmap words per batch

// ---------------------------------------------------------------------------
// Kernel A: projections (unchanged from R1 — verified absmax 0).
//   src_proj[b,s] = dot(src[b,s,:], W[0:H])
//   tgt_proj[b,t] = dot(tgt[b,t,:], W[H:2H]) + bias
// ---------------------------------------------------------------------------
__global__ __launch_bounds__(256) void proj_kernel(
    const float* __restrict__ src, const float* __restrict__ tgt,
    const float* __restrict__ W, const float* __restrict__ bptr,
    float* __restrict__ src_proj, float* __restrict__ tgt_proj)
{
    const int wave = threadIdx.x >> 6;
    const int lane = threadIdx.x & 63;
    const int row  = blockIdx.x * 4 + wave;   // 0 .. 6143

    const float* vec;
    const float* w;
    if (row < BB * SS) { vec = src + (size_t)row * HH;            w = W; }
    else               { vec = tgt + (size_t)(row - BB*SS) * HH;  w = W + HH; }
    const float4* v4 = (const float4*)vec;
    const float4* w4 = (const float4*)w;

    float acc = 0.f;
#pragma unroll
    for (int k = 0; k < 3; ++k) {
        float4 a = v4[k * 64 + lane];
        float4 b = w4[k * 64 + lane];
        acc += a.x * b.x + a.y * b.y + a.z * b.z + a.w * b.w;
    }
#pragma unroll
    for (int off = 32; off > 0; off >>= 1) acc += __shfl_down(acc, off);
    if (lane == 0) {
        if (row < BB * SS) src_proj[row] = acc;
        else               tgt_proj[row - BB * SS] = acc + bptr[0];
    }
}

// ---------------------------------------------------------------------------
// Kernel S: per-batch setup. One block per batch.
//   bitmap[b]  : bit v set iff v appears in ids[b,:]
//   prefix[b,w]: number of set bits in words [0,w)  (exclusive, per word)
//   rank_s[b,s]: rank of ids[b,s] among set bits (dense slot index)
// ---------------------------------------------------------------------------
__global__ __launch_bounds__(256) void batch_setup(
    const int* __restrict__ ids,
    unsigned* __restrict__ bm_g,          // [B, NW]
    unsigned* __restrict__ pre_g,         // [B, NW]
    unsigned short* __restrict__ rank_g)  // [B, S]
{
    __shared__ unsigned bm[NW];
    __shared__ unsigned pre[NW];
    __shared__ unsigned scan[256];
    const int b = blockIdx.x, tid = threadIdx.x;

    for (int i = tid; i < NW; i += 256) bm[i] = 0u;
    __syncthreads();
    const int* idb = ids + b * SS;
    for (int s = tid; s < SS; s += 256) {
        const int v = idb[s];
        atomicOr(&bm[v >> 5], 1u << (v & 31));
    }
    __syncthreads();

    // Each thread owns 7 consecutive words (256*7 = 1792 >= 1571).
    unsigned cnt[7];
    unsigned local = 0;
    const int w0 = tid * 7;
#pragma unroll
    for (int k = 0; k < 7; ++k) {
        const int w = w0 + k;
        cnt[k] = local;
        local += (w < NW) ? (unsigned)__popc(bm[w]) : 0u;
    }
    scan[tid] = local;
    __syncthreads();
    // Hillis-Steele inclusive scan over 256 thread sums.
    for (int off = 1; off < 256; off <<= 1) {
        const unsigned mine = scan[tid];
        const unsigned add  = (tid >= off) ? scan[tid - off] : 0u;
        __syncthreads();
        scan[tid] = mine + add;
        __syncthreads();
    }
    const unsigned excl = (tid > 0) ? scan[tid - 1] : 0u;
#pragma unroll
    for (int k = 0; k < 7; ++k) {
        const int w = w0 + k;
        if (w < NW) {
            const unsigned p = excl + cnt[k];
            pre[w] = p;
            pre_g[b * NW + w] = p;
            bm_g[b * NW + w]  = bm[w];
        }
    }
    __syncthreads();
    for (int s = tid; s < SS; s += 256) {
        const int v = idb[s];
        const unsigned w = (unsigned)v >> 5, bit = (unsigned)v & 31u;
        const unsigned r = pre[w] + (unsigned)__popc(bm[w] & ((1u << bit) - 1u));
        rank_g[b * SS + s] = (unsigned short)r;
    }
}

__device__ __forceinline__ float lut1(int v, const unsigned* bm,
                                      const unsigned* pre, const float* vals)
{
    const unsigned w = bm[v >> 5];
    const unsigned bit = (unsigned)v & 31u;
    if ((w >> bit) & 1u)
        return vals[pre[v >> 5] + (unsigned)__popc(w & ((1u << bit) - 1u))];
    return 0.f;
}

// ---------------------------------------------------------------------------
// Kernel B: one block per (b,t) row. Single-touch streaming write.
//   pass 1: vals[rank_s[s]] += attn[row,s] (LDS atomics) + p_gen dot
//   pass 2: stream the 50257-col row with float4 stores, substituting
//           vals[rank(v)] where bitmap says touched (~2% of columns).
// No global atomics; every output cacheline written exactly once.
// ---------------------------------------------------------------------------
__global__ __launch_bounds__(256) void row_kernel(
    const float* __restrict__ attn,
    const float* __restrict__ src_proj,
    const float* __restrict__ tgt_proj,
    const unsigned* __restrict__ bm_g,
    const unsigned* __restrict__ pre_g,
    const unsigned short* __restrict__ rank_g,
    float* __restrict__ out)
{
    __shared__ unsigned bm[NW];
    __shared__ unsigned pre[NW];
    __shared__ unsigned short rnk[SS];
    __shared__ float vals[SS];
    __shared__ float wsum[4];

    const int row = blockIdx.x;     // 0 .. B*T-1
    const int b   = row >> 9;       // T = 512
    const int tid = threadIdx.x;

    // Load per-batch structures (L2-hot: 512 blocks share each batch's 14.8KB)
    for (int i = tid; i < NW; i += 256) { bm[i] = bm_g[b*NW+i]; pre[i] = pre_g[b*NW+i]; }
    for (int i = tid; i < SS; i += 256) rnk[i] = rank_g[b*SS+i];
    for (int i = tid; i < SS; i += 256) vals[i] = 0.f;
    __syncthreads();

    const float* arow = attn + (size_t)row * SS;
    const float* spb  = src_proj + b * SS;
    float acc = 0.f;
#pragma unroll
    for (int k = 0; k < SS / 256; ++k) {
        const int s = tid + k * 256;
        const float a = arow[s];
        atomicAdd(&vals[rnk[s]], a);          // ds_add_f32
        acc += a * spb[s];
    }
#pragma unroll
    for (int off = 32; off > 0; off >>= 1) acc += __shfl_down(acc, off);
    if ((tid & 63) == 0) wsum[tid >> 6] = acc;
    __syncthreads();                           // vals complete + wsum visible
    if (tid == 0) {
        const float x = wsum[0] + wsum[1] + wsum[2] + wsum[3] + tgt_proj[row];
        out[row] = 1.f / (1.f + expf(-x));
    }

    // ---- streaming write of the full row ----
    float* logits = out + (BB * TT) + (size_t)row * VV;
    const uintptr_t addr = (uintptr_t)logits;
    const int head = (int)(((16u - (unsigned)(addr & 15u)) & 15u) >> 2); // 0..3
    if (tid < head) logits[tid] = lut1(tid, bm, pre, vals);

    const int n4 = (VV - head) >> 2;
    float4* p4 = (float4*)(logits + head);
    for (int i = tid; i < n4; i += 256) {
        const int v0 = head + (i << 2);        // v0 % 4 == head%4... v0&3==head&3? no: head+4i
        float4 o = make_float4(0.f, 0.f, 0.f, 0.f);
        const unsigned w  = bm[v0 >> 5];
        const unsigned sh = (unsigned)v0 & 31u;
        // head<=3 so v0&3 == head&3; sh may be non-multiple-of-4 but
        // sh <= 31-3 only if v0's 4 columns stay in one word:
        // v0 = head + 4i -> (v0 & 31) can be up to 31? If head!=0 and
        // (4i mod 32)==28+... handle straddle safely:
        unsigned nib;
        if (sh <= 28u) {
            nib = (w >> sh) & 0xFu;
        } else {
            const unsigned hi = bm[(v0 >> 5) + 1];
            nib = ((w >> sh) | (hi << (32u - sh))) & 0xFu;
        }
        if (nib) {
            o.x = lut1(v0,     bm, pre, vals);
            o.y = lut1(v0 + 1, bm, pre, vals);
            o.z = lut1(v0 + 2, bm, pre, vals);
            o.w = lut1(v0 + 3, bm, pre, vals);
        }
        p4[i] = o;
    }
    const int done = head + (n4 << 2);
    for (int v = done + tid; v < VV; v += 256)
        logits[v] = lut1(v, bm, pre, vals);
}

extern "C" void kernel_launch(void* const* d_in, const int* in_sizes, int n_in,
                              void* d_out, int out_size, void* d_ws, size_t ws_size,
                              hipStream_t stream) {
    const int*   ids  = (const int*)d_in[0];    // [B,S]
    const float* attn = (const float*)d_in[1];  // [B,T,S]
    const float* src  = (const float*)d_in[2];  // [B,S,H]
    const float* tgt  = (const float*)d_in[3];  // [B,T,H]
    const float* W    = (const float*)d_in[4];  // [2H,1]
    const float* bp   = (const float*)d_in[5];  // [1]

    float* out = (float*)d_out;                 // [B*T (p_gen) | B*T*V]

    // ws layout
    char* wsb = (char*)d_ws;
    float*          src_proj = (float*)wsb;                      // 4096 f
    float*          tgt_proj = src_proj + BB * SS;               // 2048 f
    unsigned*       bm_g     = (unsigned*)(tgt_proj + BB * TT);  // B*NW u32
    unsigned*       pre_g    = bm_g + BB * NW;                   // B*NW u32
    unsigned short* rank_g   = (unsigned short*)(pre_g + BB * NW); // B*S u16

    proj_kernel<<<(BB * SS + BB * TT) / 4, 256, 0, stream>>>(
        src, tgt, W, bp, src_proj, tgt_proj);
    batch_setup<<<BB, 256, 0, stream>>>(ids, bm_g, pre_g, rank_g);
    row_kernel<<<BB * TT, 256, 0, stream>>>(
        attn, src_proj, tgt_proj, bm_g, pre_g, rank_g, out);
}